// Round 3
// baseline (655.951 us; speedup 1.0000x reference)
//
#include <hip/hip_runtime.h>
#include <hip/hip_bf16.h>

#define PI_F 3.14159265358979323846f

// Loader insurance: keep a kernel with the stub's exact name (not launched).
__global__ void Static_82300163326800_kernel() {}

// ===================== quantum circuit (shared device code) =====================
struct M2 { float2 m00, m01, m10, m11; };

__device__ __forceinline__ int ins1(int x, int p) {
    return ((x >> p) << (p + 1)) | (x & ((1 << p) - 1));
}
__device__ __forceinline__ M2 mrx(float th) {
    float s, c; __sincosf(0.5f * th, &s, &c);
    return { make_float2(c,0.f), make_float2(0.f,-s), make_float2(0.f,-s), make_float2(c,0.f) };
}
__device__ __forceinline__ M2 mry(float th) {
    float s, c; __sincosf(0.5f * th, &s, &c);
    return { make_float2(c,0.f), make_float2(-s,0.f), make_float2(s,0.f), make_float2(c,0.f) };
}
__device__ __forceinline__ M2 mrot(float phi, float th, float om) {
    float s, c;  __sincosf(0.5f * th, &s, &c);
    float sa, ca; __sincosf(0.5f * (phi + om), &sa, &ca);
    float sd, cd; __sincosf(0.5f * (phi - om), &sd, &cd);
    return { make_float2(ca*c, -sa*c), make_float2(-cd*s, -sd*s),
             make_float2(cd*s, -sd*s), make_float2(ca*c,  sa*c) };
}
__device__ __forceinline__ M2 mu2(float phi, float lam) {
    const float r = 0.7071067811865476f;
    float sl, cl;   __sincosf(lam, &sl, &cl);
    float sp, cp;   __sincosf(phi, &sp, &cp);
    float spl, cpl; __sincosf(phi + lam, &spl, &cpl);
    return { make_float2(r,0.f), make_float2(-r*cl,-r*sl),
             make_float2(r*cp, r*sp), make_float2(r*cpl, r*spl) };
}
__device__ __forceinline__ M2 mu3(float th, float phi, float lam) {
    float s, c;     __sincosf(0.5f * th, &s, &c);
    float sl, cl;   __sincosf(lam, &sl, &cl);
    float sp, cp;   __sincosf(phi, &sp, &cp);
    float spl, cpl; __sincosf(phi + lam, &spl, &cpl);
    return { make_float2(c,0.f), make_float2(-cl*s,-sl*s),
             make_float2(cp*s, sp*s), make_float2(cpl*c, spl*c) };
}
__device__ __forceinline__ void apply1(float2* st, int t, int w, M2 m) {
    int p = 9 - w;
    int i0 = ins1(t, p), i1 = i0 | (1 << p);
    float2 a = st[i0], d = st[i1];
    st[i0] = make_float2(m.m00.x*a.x - m.m00.y*a.y + m.m01.x*d.x - m.m01.y*d.y,
                         m.m00.x*a.y + m.m00.y*a.x + m.m01.x*d.y + m.m01.y*d.x);
    st[i1] = make_float2(m.m10.x*a.x - m.m10.y*a.y + m.m11.x*d.x - m.m11.y*d.y,
                         m.m10.x*a.y + m.m10.y*a.x + m.m11.x*d.y + m.m11.y*d.x);
}
__device__ __forceinline__ void diag1(float2* st, int t, int w, float2 d0, float2 d1) {
    int p = 9 - w;
    int i0 = ins1(t, p), i1 = i0 | (1 << p);
    float2 a = st[i0], c = st[i1];
    st[i0] = make_float2(d0.x*a.x - d0.y*a.y, d0.x*a.y + d0.y*a.x);
    st[i1] = make_float2(d1.x*c.x - d1.y*c.y, d1.x*c.y + d1.y*c.x);
}
__device__ __forceinline__ void capply1(float2* st, int t, int c, int w, M2 m) {
    if (t < 256) {
        int pc = 9 - c, pw = 9 - w;
        int pl = pc < pw ? pc : pw, ph = pc + pw - pl;
        int base = ins1(ins1(t, pl), ph) | (1 << pc);
        int i0 = base, i1 = base | (1 << pw);
        float2 a = st[i0], d = st[i1];
        st[i0] = make_float2(m.m00.x*a.x - m.m00.y*a.y + m.m01.x*d.x - m.m01.y*d.y,
                             m.m00.x*a.y + m.m00.y*a.x + m.m01.x*d.y + m.m01.y*d.x);
        st[i1] = make_float2(m.m10.x*a.x - m.m10.y*a.y + m.m11.x*d.x - m.m11.y*d.y,
                             m.m10.x*a.y + m.m10.y*a.x + m.m11.x*d.y + m.m11.y*d.x);
    }
}
__device__ __forceinline__ void cdiag1(float2* st, int t, int c, int w, float2 d0, float2 d1) {
    if (t < 256) {
        int pc = 9 - c, pw = 9 - w;
        int pl = pc < pw ? pc : pw, ph = pc + pw - pl;
        int base = ins1(ins1(t, pl), ph) | (1 << pc);
        int i0 = base, i1 = base | (1 << pw);
        float2 a = st[i0], e = st[i1];
        st[i0] = make_float2(d0.x*a.x - d0.y*a.y, d0.x*a.y + d0.y*a.x);
        st[i1] = make_float2(d1.x*e.x - d1.y*e.y, d1.x*e.y + d1.y*e.x);
    }
}
__device__ __forceinline__ void cnotg(float2* st, int t, int c, int w) {
    if (t < 256) {
        int pc = 9 - c, pw = 9 - w;
        int pl = pc < pw ? pc : pw, ph = pc + pw - pl;
        int base = ins1(ins1(t, pl), ph) | (1 << pc);
        int i1 = base | (1 << pw);
        float2 a = st[base]; st[base] = st[i1]; st[i1] = a;
    }
}
__device__ __forceinline__ void czg(float2* st, int t, int c, int w) {
    if (t < 256) {
        int pc = 9 - c, pw = 9 - w;
        int pl = pc < pw ? pc : pw, ph = pc + pw - pl;
        int i = ins1(ins1(t, pl), ph) | (1 << pc) | (1 << pw);
        st[i] = make_float2(-st[i].x, -st[i].y);
    }
}
__device__ __forceinline__ void swapg(float2* st, int t, int a, int b_) {
    if (t < 256) {
        int pa = 9 - a, pb = 9 - b_;
        int pl = pa < pb ? pa : pb, ph = pa + pb - pl;
        int base = ins1(ins1(t, pl), ph);
        int iA = base | (1 << pa), iB = base | (1 << pb);
        float2 u = st[iA]; st[iA] = st[iB]; st[iB] = u;
    }
}
__device__ __forceinline__ void cswap456(float2* st, int t) {
    if (t < 128) {  // control wire4 (p=5), swap wires 5(p=4), 6(p=3)
        int base = ins1(ins1(ins1(t, 3), 4), 5) | (1 << 5);
        int iA = base | (1 << 4), iB = base | (1 << 3);
        float2 u = st[iA]; st[iA] = st[iB]; st[iB] = u;
    }
}
__device__ __forceinline__ void toff850(float2* st, int t) {
    if (t < 128) {  // controls wire8 (p=1), wire5 (p=4); target wire0 (p=9)
        int base = ins1(ins1(ins1(t, 1), 4), 9) | (1 << 1) | (1 << 4);
        int i1 = base | (1 << 9);
        float2 u = st[base]; st[base] = st[i1]; st[i1] = u;
    }
}
__device__ __forceinline__ void mrzg(float2* st, int t, int mask, float th) {
    float sh, ch; __sincosf(0.5f * th, &sh, &ch);
#pragma unroll
    for (int q = 0; q < 2; ++q) {
        int i = t + q * 512;
        float sg = (__popc(i & mask) & 1) ? sh : -sh;  // factor = ch + i*sg
        float2 a = st[i];
        st[i] = make_float2(ch*a.x - sg*a.y, ch*a.y + sg*a.x);
    }
}

// Full circuit + <Y> + log_softmax + FLOAT32 store. Called with 512 threads.
__device__ __forceinline__ void run_circ(
    float2* st, float (*red)[10], float* evs, int t, const float* ang,
    const float* q_rx, const float* q_rz3, const float* q_ps6, const float* q_rot7,
    const float* q_mrz8, const float* q_crx9, const float* q_cry10, const float* q_crz11,
    const float* q_u2, const float* q_u3, float* outf)
{
    st[t] = make_float2(t == 0 ? 1.f : 0.f, 0.f);
    st[t + 512] = make_float2(0.f, 0.f);

#pragma unroll
    for (int k = 0; k < 10; ++k) { M2 m = mrx(q_rx[k]); __syncthreads(); apply1(st, t, k, m); }
    {
        M2 mx0 = mrx(ang[0]);
#pragma unroll
        for (int k = 0; k < 10; ++k) {
            M2 m = mry(ang[k]); __syncthreads(); apply1(st, t, k, m);
            __syncthreads(); apply1(st, t, 0, mx0);
        }
    }
#pragma unroll
    for (int k = 0; k < 9; ++k) { __syncthreads(); cnotg(st, t, k, k + 1); }
    __syncthreads(); cnotg(st, t, 9, 0);

    { M2 m = mrx(ang[1]);      __syncthreads(); apply1(st, t, 1, m); }
    { M2 m = mrx(-PI_F / 4.f); __syncthreads(); apply1(st, t, 5, m); }
    { M2 m = mry(ang[2]);      __syncthreads(); apply1(st, t, 2, m); }
    { float s, c; __sincosf(0.5f * ang[3], &s, &c);
      __syncthreads(); diag1(st, t, 3, make_float2(c,-s), make_float2(c,s)); }
    __syncthreads(); diag1(st, t, 4, make_float2(1.f,0.f), make_float2(0.f,1.f));  // S
    __syncthreads(); diag1(st, t, 5, make_float2(1.f,0.f),
                           make_float2(0.7071067811865476f, 0.7071067811865476f)); // T
    { float s, c; __sincosf(0.5f * q_rz3[0], &s, &c);
      __syncthreads(); diag1(st, t, 6, make_float2(c,-s), make_float2(c,s)); }
    { M2 m = { make_float2(0.5f,0.5f), make_float2(0.5f,-0.5f),
               make_float2(0.5f,-0.5f), make_float2(0.5f,0.5f) };
      __syncthreads(); apply1(st, t, 7, m); }                                      // SX
    __syncthreads(); czg(st, t, 0, 5);
    __syncthreads(); cnotg(st, t, 0, 5);
    { M2 y = { make_float2(0.f,0.f), make_float2(0.f,-1.f),
               make_float2(0.f,1.f), make_float2(0.f,0.f) };
      __syncthreads(); capply1(st, t, 0, 5, y);
      __syncthreads(); capply1(st, t, 3, 8, y); }
    __syncthreads(); swapg(st, t, 2, 3);
    __syncthreads(); cswap456(st, t);
    __syncthreads(); toff850(st, t);
    { float s, c; __sincosf(q_ps6[0], &s, &c);
      __syncthreads(); diag1(st, t, 8, make_float2(1.f,0.f), make_float2(c,s)); }
    { float s, c; __sincosf(ang[7], &s, &c);
      __syncthreads(); diag1(st, t, 7, make_float2(1.f,0.f), make_float2(c,s)); }
    { M2 m = mrot(q_rot7[0], q_rot7[1], q_rot7[2]); __syncthreads(); apply1(st, t, 4, m); }
    { M2 m = mrot(ang[6], ang[7], ang[8]);          __syncthreads(); apply1(st, t, 5, m); }
    __syncthreads(); mrzg(st, t, 0xF8, q_mrz8[0]);  // wires (2,3,4,5,6)
    __syncthreads(); mrzg(st, t, 0x6E, ang[5]);     // wires (3,4,6,7,8)
    { M2 m = mrx(ang[6]);      __syncthreads(); capply1(st, t, 0, 1, m); }
    { M2 m = mrx(q_crx9[0]);   __syncthreads(); capply1(st, t, 4, 5, m); }
    { M2 m = mry(ang[6]);      __syncthreads(); capply1(st, t, 0, 1, m); }
    { M2 m = mry(q_cry10[0]);  __syncthreads(); capply1(st, t, 4, 5, m); }
    { float s, c; __sincosf(0.5f * ang[6], &s, &c);
      __syncthreads(); cdiag1(st, t, 0, 1, make_float2(c,-s), make_float2(c,s)); }
    { float s, c; __sincosf(0.5f * q_crz11[0], &s, &c);
      __syncthreads(); cdiag1(st, t, 4, 5, make_float2(c,-s), make_float2(c,s)); }
    { M2 m = mrot(-PI_F/4.f, PI_F/4.f, PI_F/2.f); __syncthreads(); capply1(st, t, 5, 6, m); }
    { M2 m = mrot(ang[5], ang[6], ang[7]);        __syncthreads(); capply1(st, t, 7, 8, m); }
    { float s, c; __sincosf(PI_F/7.f, &s, &c);
      __syncthreads(); diag1(st, t, 1, make_float2(1.f,0.f), make_float2(c,s)); } // U1
    { float s, c; __sincosf(ang[9], &s, &c);
      __syncthreads(); diag1(st, t, 2, make_float2(1.f,0.f), make_float2(c,s)); }
    { M2 m = mu2(q_u2[0], q_u2[1]); __syncthreads(); apply1(st, t, 8, m); }
    { M2 m = mu2(ang[0], ang[1]);   __syncthreads(); apply1(st, t, 4, m); }
    { M2 m = mu3(q_u3[0], q_u3[1], q_u3[2]); __syncthreads(); apply1(st, t, 5, m); }
    { M2 m = mu3(ang[4], ang[5], ang[6]);    __syncthreads(); apply1(st, t, 5, m); }
    __syncthreads(); cnotg(st, t, 1, 2);
    __syncthreads();

    float loc[10];
#pragma unroll
    for (int w = 0; w < 10; ++w) {
        int p = 9 - w;
        int i0 = ins1(t, p), i1 = i0 | (1 << p);
        float2 a = st[i0], c = st[i1];
        loc[w] = 2.f * (a.x * c.y - a.y * c.x);
    }
    int lane = t & 63, wv = t >> 6;
#pragma unroll
    for (int w = 0; w < 10; ++w) {
        float v = loc[w];
        v += __shfl_down(v, 32); v += __shfl_down(v, 16); v += __shfl_down(v, 8);
        v += __shfl_down(v, 4);  v += __shfl_down(v, 2);  v += __shfl_down(v, 1);
        if (lane == 0) red[wv][w] = v;
    }
    __syncthreads();
    if (t < 10) {
        float e = 0.f;
#pragma unroll
        for (int i = 0; i < 8; ++i) e += red[i][t];
        evs[t] = e;
    }
    __syncthreads();
    if (t < 10) {
        float mx = evs[0];
#pragma unroll
        for (int i = 1; i < 10; ++i) mx = fmaxf(mx, evs[i]);
        float ss = 0.f;
#pragma unroll
        for (int i = 0; i < 10; ++i) ss += expf(evs[i] - mx);
        outf[t] = evs[t] - mx - logf(ss);    // FLOAT32 output
    }
}

// ===================== conv stage (runs in LDS buf[9216]) =====================
template <int NT>
__device__ __forceinline__ void conv_stage(
    float* buf, int n, int t,
    const float* __restrict__ x, const float* __restrict__ w1, const float* __restrict__ b1,
    const float* __restrict__ w2, const float* __restrict__ b2)
{
    float* xs  = buf;            // 784
    float* w1s = buf + 784;      // 288
    float* h1s = buf + 1072;     // 676
    float* w2s = buf + 1748;     // 576
    const int ocq = t / 24, r = t - ocq * 24;
    const bool active = (t < 384);

    for (int i = t; i < 784; i += NT) xs[i] = x[n * 784 + i];
    for (int i = t; i < 288; i += NT) w1s[i] = w1[i];

    float acc[4][24];
#pragma unroll
    for (int j = 0; j < 4; ++j)
#pragma unroll
        for (int xo = 0; xo < 24; ++xo) acc[j][xo] = 0.f;

    for (int ic = 0; ic < 32; ++ic) {
        __syncthreads();
        float bb1 = b1[ic];
        for (int i = t; i < 676; i += NT) {
            int yy = i / 26, xx = i - yy * 26;
            const float* xp = xs + yy * 28 + xx;
            const float* wp = w1s + ic * 9;
            float s = bb1;
#pragma unroll
            for (int ky = 0; ky < 3; ++ky)
#pragma unroll
                for (int kx = 0; kx < 3; ++kx)
                    s += xp[ky * 28 + kx] * wp[ky * 3 + kx];
            h1s[i] = fmaxf(s, 0.f);
        }
        for (int i = t; i < 576; i += NT) {
            int oc = i / 9, k = i - oc * 9;
            w2s[i] = w2[oc * 288 + ic * 9 + k];
        }
        __syncthreads();
        if (active) {
            float wr[4][9];
#pragma unroll
            for (int j = 0; j < 4; ++j)
#pragma unroll
                for (int k = 0; k < 9; ++k)
                    wr[j][k] = w2s[(ocq * 4 + j) * 9 + k];
            float c0[3], c1[3];
#pragma unroll
            for (int q = 0; q < 3; ++q) { c0[q] = h1s[(r + q) * 26]; c1[q] = h1s[(r + q) * 26 + 1]; }
#pragma unroll
            for (int xo = 0; xo < 24; ++xo) {
                float c2[3];
#pragma unroll
                for (int q = 0; q < 3; ++q) c2[q] = h1s[(r + q) * 26 + xo + 2];
#pragma unroll
                for (int j = 0; j < 4; ++j) {
                    acc[j][xo] += wr[j][0]*c0[0] + wr[j][1]*c1[0] + wr[j][2]*c2[0]
                                + wr[j][3]*c0[1] + wr[j][4]*c1[1] + wr[j][5]*c2[1]
                                + wr[j][6]*c0[2] + wr[j][7]*c1[2] + wr[j][8]*c2[2];
                }
#pragma unroll
                for (int q = 0; q < 3; ++q) { c0[q] = c1[q]; c1[q] = c2[q]; }
            }
        }
    }
    __syncthreads();
    if (active && (r & 1)) {
#pragma unroll
        for (int j = 0; j < 4; ++j) {
            int oc = ocq * 4 + j;
            float bb = b2[oc];
#pragma unroll
            for (int px = 0; px < 12; ++px) {
                float v0 = fmaxf(acc[j][2*px]   + bb, 0.f);
                float v1 = fmaxf(acc[j][2*px+1] + bb, 0.f);
                buf[oc * 144 + (r >> 1) * 12 + px] = fmaxf(v0, v1);
            }
        }
    }
    __syncthreads();
    if (active && !(r & 1)) {
#pragma unroll
        for (int j = 0; j < 4; ++j) {
            int oc = ocq * 4 + j;
            float bb = b2[oc];
#pragma unroll
            for (int px = 0; px < 12; ++px) {
                float v0 = fmaxf(acc[j][2*px]   + bb, 0.f);
                float v1 = fmaxf(acc[j][2*px+1] + bb, 0.f);
                int idx = oc * 144 + (r >> 1) * 12 + px;
                buf[idx] = fmaxf(fmaxf(v0, v1), buf[idx]);
            }
        }
    }
    __syncthreads();
}

// ===================== FAST PATH kernels (need 42 MB workspace) =====================
__global__ __launch_bounds__(384) void convnet_kernel(
    const float* __restrict__ x, const float* __restrict__ w1, const float* __restrict__ b1,
    const float* __restrict__ w2, const float* __restrict__ b2, float* __restrict__ flat)
{
    __shared__ float buf[9216];
    const int n = blockIdx.x, t = threadIdx.x;
    conv_stage<384>(buf, n, t, x, w1, b1, w2, b2);
    for (int i = t; i < 9216; i += 384) flat[(size_t)n * 9216 + i] = buf[i];
}

__global__ __launch_bounds__(256) void fc1_kernel(
    const float* __restrict__ A, const float* __restrict__ B, float* __restrict__ part)
{
    __shared__ float As[16][68];
    __shared__ float Bs[16][68];
    const int m0 = blockIdx.x * 64, n0 = blockIdx.y * 64, kb = blockIdx.z;
    const int t = threadIdx.x;
    const int tm = t & 15, tn = t >> 4;
    const int lrow = t >> 2, lk = (t & 3) * 4;
    const int k0 = kb * 1152;
    float acc[4][4];
#pragma unroll
    for (int i = 0; i < 4; ++i)
#pragma unroll
        for (int j = 0; j < 4; ++j) acc[i][j] = 0.f;

    const float* ap = A + (size_t)(m0 + lrow) * 9216 + k0 + lk;
    const float* bp = B + (size_t)(n0 + lrow) * 9216 + k0 + lk;
    for (int ks = 0; ks < 1152; ks += 16) {
        __syncthreads();
        float4 av = *(const float4*)(ap + ks);
        float4 bv = *(const float4*)(bp + ks);
        As[lk+0][lrow] = av.x; As[lk+1][lrow] = av.y; As[lk+2][lrow] = av.z; As[lk+3][lrow] = av.w;
        Bs[lk+0][lrow] = bv.x; Bs[lk+1][lrow] = bv.y; Bs[lk+2][lrow] = bv.z; Bs[lk+3][lrow] = bv.w;
        __syncthreads();
#pragma unroll
        for (int kk = 0; kk < 16; ++kk) {
            float4 a = *(const float4*)&As[kk][tm * 4];
            float4 b = *(const float4*)&Bs[kk][tn * 4];
            acc[0][0] += a.x*b.x; acc[0][1] += a.x*b.y; acc[0][2] += a.x*b.z; acc[0][3] += a.x*b.w;
            acc[1][0] += a.y*b.x; acc[1][1] += a.y*b.y; acc[1][2] += a.y*b.z; acc[1][3] += a.y*b.w;
            acc[2][0] += a.z*b.x; acc[2][1] += a.z*b.y; acc[2][2] += a.z*b.z; acc[2][3] += a.z*b.w;
            acc[3][0] += a.w*b.x; acc[3][1] += a.w*b.y; acc[3][2] += a.w*b.z; acc[3][3] += a.w*b.w;
        }
    }
#pragma unroll
    for (int i = 0; i < 4; ++i)
#pragma unroll
        for (int j = 0; j < 4; ++j)
            part[(size_t)kb * 131072 + (size_t)(m0 + tm * 4 + i) * 128 + (n0 + tn * 4 + j)] = acc[i][j];
}

__global__ __launch_bounds__(128) void fc2_kernel(
    const float* __restrict__ part, const float* __restrict__ fb1,
    const float* __restrict__ fw2, const float* __restrict__ fb2, float* __restrict__ angO)
{
    __shared__ float h[128];
    const int b = blockIdx.x, t = threadIdx.x;
    float s = fb1[t];
#pragma unroll
    for (int kb = 0; kb < 8; ++kb) s += part[(size_t)kb * 131072 + b * 128 + t];
    h[t] = fmaxf(s, 0.f);
    __syncthreads();
    if (t < 10) {
        float d = fb2[t];
#pragma unroll 16
        for (int k = 0; k < 128; ++k) d += h[k] * fw2[t * 128 + k];
        angO[b * 10 + t] = 6.283185307179586f / (1.f + expf(-d));
    }
}

__global__ __launch_bounds__(512) void circuit_kernel(
    const float* __restrict__ ang_g,
    const float* __restrict__ q_rx, const float* __restrict__ q_rz3,
    const float* __restrict__ q_ps6, const float* __restrict__ q_rot7,
    const float* __restrict__ q_mrz8, const float* __restrict__ q_crx9,
    const float* __restrict__ q_cry10, const float* __restrict__ q_crz11,
    const float* __restrict__ q_u2, const float* __restrict__ q_u3,
    float* __restrict__ out)
{
    __shared__ float2 st[1024];
    __shared__ float red[8][10];
    __shared__ float evs[10];
    const int b = blockIdx.x, t = threadIdx.x;
    float a[10];
#pragma unroll
    for (int j = 0; j < 10; ++j) a[j] = ang_g[b * 10 + j];
    run_circ(st, red, evs, t, a, q_rx, q_rz3, q_ps6, q_rot7, q_mrz8,
             q_crx9, q_cry10, q_crz11, q_u2, q_u3, out + b * 10);
}

// ===================== FALLBACK: fully fused, zero workspace =====================
__global__ __launch_bounds__(512) void fused_kernel(
    const float* __restrict__ x, const float* __restrict__ w1, const float* __restrict__ b1,
    const float* __restrict__ w2, const float* __restrict__ b2,
    const float* __restrict__ fw1, const float* __restrict__ fb1,
    const float* __restrict__ fw2, const float* __restrict__ fb2,
    const float* __restrict__ q_rx, const float* __restrict__ q_rz3,
    const float* __restrict__ q_ps6, const float* __restrict__ q_rot7,
    const float* __restrict__ q_mrz8, const float* __restrict__ q_crx9,
    const float* __restrict__ q_cry10, const float* __restrict__ q_crz11,
    const float* __restrict__ q_u2, const float* __restrict__ q_u3,
    float* __restrict__ out)
{
    __shared__ float buf[9216];
    __shared__ float2 st[1024];
    __shared__ float hred[512];
    __shared__ float hvec[128];
    __shared__ float angs[10];
    __shared__ float red[8][10];
    __shared__ float evs[10];
    const int n = blockIdx.x, t = threadIdx.x;

    conv_stage<512>(buf, n, t, x, w1, b1, w2, b2);

    {
        const int j = t >> 2, q = t & 3;
        const float* wrow = fw1 + (size_t)j * 9216 + q * 2304;
        const float* arow = buf + q * 2304;
        float s = 0.f;
        for (int k = 0; k < 2304; k += 4) {
            float4 w = *(const float4*)(wrow + k);
            s += w.x * arow[k] + w.y * arow[k+1] + w.z * arow[k+2] + w.w * arow[k+3];
        }
        hred[t] = s;
    }
    __syncthreads();
    if (t < 128)
        hvec[t] = fmaxf(fb1[t] + hred[t*4] + hred[t*4+1] + hred[t*4+2] + hred[t*4+3], 0.f);
    __syncthreads();
    if (t < 10) {
        float d = fb2[t];
#pragma unroll 16
        for (int k = 0; k < 128; ++k) d += hvec[k] * fw2[t * 128 + k];
        angs[t] = 6.283185307179586f / (1.f + expf(-d));
    }
    __syncthreads();
    run_circ(st, red, evs, t, angs, q_rx, q_rz3, q_ps6, q_rot7, q_mrz8,
             q_crx9, q_cry10, q_crz11, q_u2, q_u3, out + n * 10);
}

// ===================== launch =====================
extern "C" void kernel_launch(void* const* d_in, const int* in_sizes, int n_in,
                              void* d_out, int out_size, void* d_ws, size_t ws_size,
                              hipStream_t stream)
{
    (void)in_sizes; (void)n_in;
    const float* x    = (const float*)d_in[0];
    const float* w1   = (const float*)d_in[1];
    const float* b1   = (const float*)d_in[2];
    const float* w2   = (const float*)d_in[3];
    const float* b2   = (const float*)d_in[4];
    const float* fw1  = (const float*)d_in[5];
    const float* fb1  = (const float*)d_in[6];
    const float* fw2  = (const float*)d_in[7];
    const float* fb2  = (const float*)d_in[8];
    const float* qrx  = (const float*)d_in[9];
    const float* qrz3 = (const float*)d_in[10];
    const float* qps6 = (const float*)d_in[11];
    const float* qrot7 = (const float*)d_in[12];
    const float* qmrz8 = (const float*)d_in[13];
    const float* qcrx9 = (const float*)d_in[14];
    const float* qcry10 = (const float*)d_in[15];
    const float* qcrz11 = (const float*)d_in[16];
    const float* qu2  = (const float*)d_in[17];
    const float* qu3  = (const float*)d_in[18];
    float* out = (float*)d_out;

    // Diagnostic sentinel: pattern 0x40 over out_size*2 bytes (safe under either
    // dtype interpretation). Kernels fully overwrite all out_size floats after.
    // If the final error is ~5.4 -> kernel_launch ran but launches were dropped.
    // If exactly 2.375 -> kernel_launch was never called (infra).
    (void)hipMemsetAsync(d_out, 0x40, (size_t)out_size * 2, stream);
    (void)hipGetLastError();  // clear any stale error

    const size_t need = (size_t)1024 * 9216 * 4
                      + (size_t)8 * 1024 * 128 * 4
                      + (size_t)1024 * 10 * 4;
    if (ws_size >= need) {
        float* flat = (float*)d_ws;
        float* part = flat + (size_t)1024 * 9216;
        float* angb = part + (size_t)8 * 1024 * 128;
        convnet_kernel<<<1024, 384, 0, stream>>>(x, w1, b1, w2, b2, flat);
        fc1_kernel<<<dim3(16, 2, 8), 256, 0, stream>>>(flat, fw1, part);
        fc2_kernel<<<1024, 128, 0, stream>>>(part, fb1, fw2, fb2, angb);
        circuit_kernel<<<1024, 512, 0, stream>>>(angb, qrx, qrz3, qps6, qrot7, qmrz8,
                                                 qcrx9, qcry10, qcrz11, qu2, qu3, out);
    } else {
        fused_kernel<<<1024, 512, 0, stream>>>(x, w1, b1, w2, b2, fw1, fb1, fw2, fb2,
                                               qrx, qrz3, qps6, qrot7, qmrz8,
                                               qcrx9, qcry10, qcrz11, qu2, qu3, out);
    }
    // If any launch reported an error, flood the output with an unmistakable
    // sentinel (~3.4e38) so the bench reports a distinctive absmax.
    if (hipGetLastError() != hipSuccess) {
        (void)hipMemsetAsync(d_out, 0x7F, (size_t)out_size * 2, stream);
    }
}

// Round 4
// 236.931 us; speedup vs baseline: 2.7685x; 2.7685x over previous
//
#include <hip/hip_runtime.h>
#include <hip/hip_bf16.h>

#define PI_F 3.14159265358979323846f

// Loader insurance: keep a kernel with the stub's exact name (not launched).
__global__ void Static_82300163326800_kernel() {}

typedef short bf16x8 __attribute__((ext_vector_type(8)));
typedef float f32x4 __attribute__((ext_vector_type(4)));

__device__ __forceinline__ unsigned short f2bf(float v) {
    __hip_bfloat16 hb = __float2bfloat16(v);
    return *reinterpret_cast<unsigned short*>(&hb);
}

// ===================== quantum circuit (shared device code) =====================
struct M2 { float2 m00, m01, m10, m11; };

__device__ __forceinline__ int ins1(int x, int p) {
    return ((x >> p) << (p + 1)) | (x & ((1 << p) - 1));
}
__device__ __forceinline__ M2 mrx(float th) {
    float s, c; __sincosf(0.5f * th, &s, &c);
    return { make_float2(c,0.f), make_float2(0.f,-s), make_float2(0.f,-s), make_float2(c,0.f) };
}
__device__ __forceinline__ M2 mry(float th) {
    float s, c; __sincosf(0.5f * th, &s, &c);
    return { make_float2(c,0.f), make_float2(-s,0.f), make_float2(s,0.f), make_float2(c,0.f) };
}
__device__ __forceinline__ M2 mrot(float phi, float th, float om) {
    float s, c;  __sincosf(0.5f * th, &s, &c);
    float sa, ca; __sincosf(0.5f * (phi + om), &sa, &ca);
    float sd, cd; __sincosf(0.5f * (phi - om), &sd, &cd);
    return { make_float2(ca*c, -sa*c), make_float2(-cd*s, -sd*s),
             make_float2(cd*s, -sd*s), make_float2(ca*c,  sa*c) };
}
__device__ __forceinline__ M2 mu2(float phi, float lam) {
    const float r = 0.7071067811865476f;
    float sl, cl;   __sincosf(lam, &sl, &cl);
    float sp, cp;   __sincosf(phi, &sp, &cp);
    float spl, cpl; __sincosf(phi + lam, &spl, &cpl);
    return { make_float2(r,0.f), make_float2(-r*cl,-r*sl),
             make_float2(r*cp, r*sp), make_float2(r*cpl, r*spl) };
}
__device__ __forceinline__ M2 mu3(float th, float phi, float lam) {
    float s, c;     __sincosf(0.5f * th, &s, &c);
    float sl, cl;   __sincosf(lam, &sl, &cl);
    float sp, cp;   __sincosf(phi, &sp, &cp);
    float spl, cpl; __sincosf(phi + lam, &spl, &cpl);
    return { make_float2(c,0.f), make_float2(-cl*s,-sl*s),
             make_float2(cp*s, sp*s), make_float2(cpl*c, spl*c) };
}
__device__ __forceinline__ void apply1(float2* st, int t, int w, M2 m) {
    int p = 9 - w;
    int i0 = ins1(t, p), i1 = i0 | (1 << p);
    float2 a = st[i0], d = st[i1];
    st[i0] = make_float2(m.m00.x*a.x - m.m00.y*a.y + m.m01.x*d.x - m.m01.y*d.y,
                         m.m00.x*a.y + m.m00.y*a.x + m.m01.x*d.y + m.m01.y*d.x);
    st[i1] = make_float2(m.m10.x*a.x - m.m10.y*a.y + m.m11.x*d.x - m.m11.y*d.y,
                         m.m10.x*a.y + m.m10.y*a.x + m.m11.x*d.y + m.m11.y*d.x);
}
__device__ __forceinline__ void diag1(float2* st, int t, int w, float2 d0, float2 d1) {
    int p = 9 - w;
    int i0 = ins1(t, p), i1 = i0 | (1 << p);
    float2 a = st[i0], c = st[i1];
    st[i0] = make_float2(d0.x*a.x - d0.y*a.y, d0.x*a.y + d0.y*a.x);
    st[i1] = make_float2(d1.x*c.x - d1.y*c.y, d1.x*c.y + d1.y*c.x);
}
__device__ __forceinline__ void capply1(float2* st, int t, int c, int w, M2 m) {
    if (t < 256) {
        int pc = 9 - c, pw = 9 - w;
        int pl = pc < pw ? pc : pw, ph = pc + pw - pl;
        int base = ins1(ins1(t, pl), ph) | (1 << pc);
        int i0 = base, i1 = base | (1 << pw);
        float2 a = st[i0], d = st[i1];
        st[i0] = make_float2(m.m00.x*a.x - m.m00.y*a.y + m.m01.x*d.x - m.m01.y*d.y,
                             m.m00.x*a.y + m.m00.y*a.x + m.m01.x*d.y + m.m01.y*d.x);
        st[i1] = make_float2(m.m10.x*a.x - m.m10.y*a.y + m.m11.x*d.x - m.m11.y*d.y,
                             m.m10.x*a.y + m.m10.y*a.x + m.m11.x*d.y + m.m11.y*d.x);
    }
}
__device__ __forceinline__ void cdiag1(float2* st, int t, int c, int w, float2 d0, float2 d1) {
    if (t < 256) {
        int pc = 9 - c, pw = 9 - w;
        int pl = pc < pw ? pc : pw, ph = pc + pw - pl;
        int base = ins1(ins1(t, pl), ph) | (1 << pc);
        int i0 = base, i1 = base | (1 << pw);
        float2 a = st[i0], e = st[i1];
        st[i0] = make_float2(d0.x*a.x - d0.y*a.y, d0.x*a.y + d0.y*a.x);
        st[i1] = make_float2(d1.x*e.x - d1.y*e.y, d1.x*e.y + d1.y*e.x);
    }
}
__device__ __forceinline__ void cnotg(float2* st, int t, int c, int w) {
    if (t < 256) {
        int pc = 9 - c, pw = 9 - w;
        int pl = pc < pw ? pc : pw, ph = pc + pw - pl;
        int base = ins1(ins1(t, pl), ph) | (1 << pc);
        int i1 = base | (1 << pw);
        float2 a = st[base]; st[base] = st[i1]; st[i1] = a;
    }
}
__device__ __forceinline__ void czg(float2* st, int t, int c, int w) {
    if (t < 256) {
        int pc = 9 - c, pw = 9 - w;
        int pl = pc < pw ? pc : pw, ph = pc + pw - pl;
        int i = ins1(ins1(t, pl), ph) | (1 << pc) | (1 << pw);
        st[i] = make_float2(-st[i].x, -st[i].y);
    }
}
__device__ __forceinline__ void swapg(float2* st, int t, int a, int b_) {
    if (t < 256) {
        int pa = 9 - a, pb = 9 - b_;
        int pl = pa < pb ? pa : pb, ph = pa + pb - pl;
        int base = ins1(ins1(t, pl), ph);
        int iA = base | (1 << pa), iB = base | (1 << pb);
        float2 u = st[iA]; st[iA] = st[iB]; st[iB] = u;
    }
}
__device__ __forceinline__ void cswap456(float2* st, int t) {
    if (t < 128) {
        int base = ins1(ins1(ins1(t, 3), 4), 5) | (1 << 5);
        int iA = base | (1 << 4), iB = base | (1 << 3);
        float2 u = st[iA]; st[iA] = st[iB]; st[iB] = u;
    }
}
__device__ __forceinline__ void toff850(float2* st, int t) {
    if (t < 128) {
        int base = ins1(ins1(ins1(t, 1), 4), 9) | (1 << 1) | (1 << 4);
        int i1 = base | (1 << 9);
        float2 u = st[base]; st[base] = st[i1]; st[i1] = u;
    }
}
__device__ __forceinline__ void mrzg(float2* st, int t, int mask, float th) {
    float sh, ch; __sincosf(0.5f * th, &sh, &ch);
#pragma unroll
    for (int q = 0; q < 2; ++q) {
        int i = t + q * 512;
        float sg = (__popc(i & mask) & 1) ? sh : -sh;
        float2 a = st[i];
        st[i] = make_float2(ch*a.x - sg*a.y, ch*a.y + sg*a.x);
    }
}

__device__ __forceinline__ void run_circ(
    float2* st, float (*red)[10], float* evs, int t, const float* ang,
    const float* q_rx, const float* q_rz3, const float* q_ps6, const float* q_rot7,
    const float* q_mrz8, const float* q_crx9, const float* q_cry10, const float* q_crz11,
    const float* q_u2, const float* q_u3, float* outf)
{
    st[t] = make_float2(t == 0 ? 1.f : 0.f, 0.f);
    st[t + 512] = make_float2(0.f, 0.f);

#pragma unroll
    for (int k = 0; k < 10; ++k) { M2 m = mrx(q_rx[k]); __syncthreads(); apply1(st, t, k, m); }
    {
        M2 mx0 = mrx(ang[0]);
#pragma unroll
        for (int k = 0; k < 10; ++k) {
            M2 m = mry(ang[k]); __syncthreads(); apply1(st, t, k, m);
            __syncthreads(); apply1(st, t, 0, mx0);
        }
    }
#pragma unroll
    for (int k = 0; k < 9; ++k) { __syncthreads(); cnotg(st, t, k, k + 1); }
    __syncthreads(); cnotg(st, t, 9, 0);

    { M2 m = mrx(ang[1]);      __syncthreads(); apply1(st, t, 1, m); }
    { M2 m = mrx(-PI_F / 4.f); __syncthreads(); apply1(st, t, 5, m); }
    { M2 m = mry(ang[2]);      __syncthreads(); apply1(st, t, 2, m); }
    { float s, c; __sincosf(0.5f * ang[3], &s, &c);
      __syncthreads(); diag1(st, t, 3, make_float2(c,-s), make_float2(c,s)); }
    __syncthreads(); diag1(st, t, 4, make_float2(1.f,0.f), make_float2(0.f,1.f));  // S
    __syncthreads(); diag1(st, t, 5, make_float2(1.f,0.f),
                           make_float2(0.7071067811865476f, 0.7071067811865476f)); // T
    { float s, c; __sincosf(0.5f * q_rz3[0], &s, &c);
      __syncthreads(); diag1(st, t, 6, make_float2(c,-s), make_float2(c,s)); }
    { M2 m = { make_float2(0.5f,0.5f), make_float2(0.5f,-0.5f),
               make_float2(0.5f,-0.5f), make_float2(0.5f,0.5f) };
      __syncthreads(); apply1(st, t, 7, m); }                                      // SX
    __syncthreads(); czg(st, t, 0, 5);
    __syncthreads(); cnotg(st, t, 0, 5);
    { M2 y = { make_float2(0.f,0.f), make_float2(0.f,-1.f),
               make_float2(0.f,1.f), make_float2(0.f,0.f) };
      __syncthreads(); capply1(st, t, 0, 5, y);
      __syncthreads(); capply1(st, t, 3, 8, y); }
    __syncthreads(); swapg(st, t, 2, 3);
    __syncthreads(); cswap456(st, t);
    __syncthreads(); toff850(st, t);
    { float s, c; __sincosf(q_ps6[0], &s, &c);
      __syncthreads(); diag1(st, t, 8, make_float2(1.f,0.f), make_float2(c,s)); }
    { float s, c; __sincosf(ang[7], &s, &c);
      __syncthreads(); diag1(st, t, 7, make_float2(1.f,0.f), make_float2(c,s)); }
    { M2 m = mrot(q_rot7[0], q_rot7[1], q_rot7[2]); __syncthreads(); apply1(st, t, 4, m); }
    { M2 m = mrot(ang[6], ang[7], ang[8]);          __syncthreads(); apply1(st, t, 5, m); }
    __syncthreads(); mrzg(st, t, 0xF8, q_mrz8[0]);  // wires (2,3,4,5,6)
    __syncthreads(); mrzg(st, t, 0x6E, ang[5]);     // wires (3,4,6,7,8)
    { M2 m = mrx(ang[6]);      __syncthreads(); capply1(st, t, 0, 1, m); }
    { M2 m = mrx(q_crx9[0]);   __syncthreads(); capply1(st, t, 4, 5, m); }
    { M2 m = mry(ang[6]);      __syncthreads(); capply1(st, t, 0, 1, m); }
    { M2 m = mry(q_cry10[0]);  __syncthreads(); capply1(st, t, 4, 5, m); }
    { float s, c; __sincosf(0.5f * ang[6], &s, &c);
      __syncthreads(); cdiag1(st, t, 0, 1, make_float2(c,-s), make_float2(c,s)); }
    { float s, c; __sincosf(0.5f * q_crz11[0], &s, &c);
      __syncthreads(); cdiag1(st, t, 4, 5, make_float2(c,-s), make_float2(c,s)); }
    { M2 m = mrot(-PI_F/4.f, PI_F/4.f, PI_F/2.f); __syncthreads(); capply1(st, t, 5, 6, m); }
    { M2 m = mrot(ang[5], ang[6], ang[7]);        __syncthreads(); capply1(st, t, 7, 8, m); }
    { float s, c; __sincosf(PI_F/7.f, &s, &c);
      __syncthreads(); diag1(st, t, 1, make_float2(1.f,0.f), make_float2(c,s)); } // U1
    { float s, c; __sincosf(ang[9], &s, &c);
      __syncthreads(); diag1(st, t, 2, make_float2(1.f,0.f), make_float2(c,s)); }
    { M2 m = mu2(q_u2[0], q_u2[1]); __syncthreads(); apply1(st, t, 8, m); }
    { M2 m = mu2(ang[0], ang[1]);   __syncthreads(); apply1(st, t, 4, m); }
    { M2 m = mu3(q_u3[0], q_u3[1], q_u3[2]); __syncthreads(); apply1(st, t, 5, m); }
    { M2 m = mu3(ang[4], ang[5], ang[6]);    __syncthreads(); apply1(st, t, 5, m); }
    __syncthreads(); cnotg(st, t, 1, 2);
    __syncthreads();

    float loc[10];
#pragma unroll
    for (int w = 0; w < 10; ++w) {
        int p = 9 - w;
        int i0 = ins1(t, p), i1 = i0 | (1 << p);
        float2 a = st[i0], c = st[i1];
        loc[w] = 2.f * (a.x * c.y - a.y * c.x);
    }
    int lane = t & 63, wv = t >> 6;
#pragma unroll
    for (int w = 0; w < 10; ++w) {
        float v = loc[w];
        v += __shfl_down(v, 32); v += __shfl_down(v, 16); v += __shfl_down(v, 8);
        v += __shfl_down(v, 4);  v += __shfl_down(v, 2);  v += __shfl_down(v, 1);
        if (lane == 0) red[wv][w] = v;
    }
    __syncthreads();
    if (t < 10) {
        float e = 0.f;
#pragma unroll
        for (int i = 0; i < 8; ++i) e += red[i][t];
        evs[t] = e;
    }
    __syncthreads();
    if (t < 10) {
        float mx = evs[0];
#pragma unroll
        for (int i = 1; i < 10; ++i) mx = fmaxf(mx, evs[i]);
        float ss = 0.f;
#pragma unroll
        for (int i = 0; i < 10; ++i) ss += expf(evs[i] - mx);
        outf[t] = evs[t] - mx - logf(ss);
    }
}

// ===================== prep: w2 [64][32][3][3] fp32 -> w2t [64][9*32] bf16 ==========
__global__ __launch_bounds__(256) void prep_w2(
    const float* __restrict__ w2, unsigned short* __restrict__ w2t)
{
    int idx = blockIdx.x * 256 + threadIdx.x;
    if (idx < 18432) {
        int oc = idx / 288, r = idx - oc * 288;
        int s = r >> 5, ic = r & 31;
        w2t[idx] = f2bf(w2[oc * 288 + ic * 9 + s]);
    }
}

// ===================== MFMA convnet: conv1(fp32)->bf16 LDS, conv2 via MFMA ==========
// grid 1024 (one image per block), block 256 (4 waves).
// conv2 GEMM: M=576 px, N=64 oc, K=288=(ky,kx)x32ic. M-tile = 2 rows x 8 cols so a
// lane's 4 C-regs (rows quad*4+reg) form one 2x2 pool window -> fused bias/relu/pool.
__global__ __launch_bounds__(256, 2) void convnet_mfma(
    const float* __restrict__ x, const float* __restrict__ w1, const float* __restrict__ b1,
    const unsigned short* __restrict__ w2t, const float* __restrict__ b2,
    float* __restrict__ flat)
{
    __shared__ float xs[784];
    __shared__ float w1s[288];
    __shared__ __align__(16) unsigned short h1t[676 * 40];  // [pix][ic], stride 40 (16B-aligned, bank-spread)
    const int n = blockIdx.x, t = threadIdx.x;
    const int lane = t & 63, wv = t >> 6;
    const int m = lane & 15, quad = lane >> 4;

    for (int i = t; i < 784; i += 256) xs[i] = x[n * 784 + i];
    for (int i = t; i < 288; i += 256) w1s[i] = w1[i];

    // hoist all 36 B fragments (4 n-tiles x 9 k-steps) from global (L2-resident)
    bf16x8 bq[9][4];
#pragma unroll
    for (int s = 0; s < 9; ++s)
#pragma unroll
        for (int nt = 0; nt < 4; ++nt)
            bq[s][nt] = *(const bf16x8*)(w2t + (nt * 16 + m) * 288 + s * 32 + quad * 8);

    __syncthreads();

    // conv1 (fused recompute): thread owns ic = t&31, pix = t>>5 + 8*it
    {
        const int ic = t & 31;
        float wr[9];
#pragma unroll
        for (int k = 0; k < 9; ++k) wr[k] = w1s[ic * 9 + k];
        const float bb = b1[ic];
        for (int pix = (t >> 5); pix < 676; pix += 8) {
            int yy = pix / 26, xx = pix - yy * 26;
            const float* xp = xs + yy * 28 + xx;
            float s = bb;
            s += xp[0]*wr[0]  + xp[1]*wr[1]  + xp[2]*wr[2]
               + xp[28]*wr[3] + xp[29]*wr[4] + xp[30]*wr[5]
               + xp[56]*wr[6] + xp[57]*wr[7] + xp[58]*wr[8];
            h1t[pix * 40 + ic] = f2bf(fmaxf(s, 0.f));
        }
    }
    __syncthreads();

    float bb2[4];
#pragma unroll
    for (int nt = 0; nt < 4; ++nt) bb2[nt] = b2[nt * 16 + m];

    float* outp = flat + (size_t)n * 9216;

    for (int q = 0; q < 9; ++q) {
        const int mt = wv + q * 4;               // 36 M-tiles over 4 waves
        const int a = mt / 3, b3 = mt - a * 3;   // tile = rows {2a,2a+1} x cols {8*b3..8*b3+7}
        const int y0 = 2 * a + (m & 1), x0 = 8 * b3 + (m >> 1);  // A-row for THIS lane
        f32x4 acc[4] = {};
#pragma unroll
        for (int s = 0; s < 9; ++s) {
            const int ky = s / 3, kx = s - ky * 3;
            bf16x8 af = *(const bf16x8*)&h1t[((y0 + ky) * 26 + x0 + kx) * 40 + quad * 8];
#pragma unroll
            for (int nt = 0; nt < 4; ++nt)
                acc[nt] = __builtin_amdgcn_mfma_f32_16x16x32_bf16(af, bq[s][nt], acc[nt], 0, 0, 0);
        }
        // D rows quad*4+reg: reg&1 -> y-offset, quad*2+(reg>>1) -> x-offset: regs = 2x2 window
        const int pooled_idx = a * 12 + 4 * b3 + quad;
#pragma unroll
        for (int nt = 0; nt < 4; ++nt) {
            float v = fmaxf(fmaxf(acc[nt][0], acc[nt][1]), fmaxf(acc[nt][2], acc[nt][3]));
            outp[(nt * 16 + m) * 144 + pooled_idx] = fmaxf(v + bb2[nt], 0.f);
        }
    }
}

// ===================== fc1: [1024,9216] @ [128,9216]^T, K split 8 =====================
__global__ __launch_bounds__(256) void fc1_kernel(
    const float* __restrict__ A, const float* __restrict__ B, float* __restrict__ part)
{
    __shared__ float As[16][68];
    __shared__ float Bs[16][68];
    const int m0 = blockIdx.x * 64, n0 = blockIdx.y * 64, kb = blockIdx.z;
    const int t = threadIdx.x;
    const int tm = t & 15, tn = t >> 4;
    const int lrow = t >> 2, lk = (t & 3) * 4;
    const int k0 = kb * 1152;
    float acc[4][4];
#pragma unroll
    for (int i = 0; i < 4; ++i)
#pragma unroll
        for (int j = 0; j < 4; ++j) acc[i][j] = 0.f;

    const float* ap = A + (size_t)(m0 + lrow) * 9216 + k0 + lk;
    const float* bp = B + (size_t)(n0 + lrow) * 9216 + k0 + lk;
    for (int ks = 0; ks < 1152; ks += 16) {
        __syncthreads();
        float4 av = *(const float4*)(ap + ks);
        float4 bv = *(const float4*)(bp + ks);
        As[lk+0][lrow] = av.x; As[lk+1][lrow] = av.y; As[lk+2][lrow] = av.z; As[lk+3][lrow] = av.w;
        Bs[lk+0][lrow] = bv.x; Bs[lk+1][lrow] = bv.y; Bs[lk+2][lrow] = bv.z; Bs[lk+3][lrow] = bv.w;
        __syncthreads();
#pragma unroll
        for (int kk = 0; kk < 16; ++kk) {
            float4 a = *(const float4*)&As[kk][tm * 4];
            float4 b = *(const float4*)&Bs[kk][tn * 4];
            acc[0][0] += a.x*b.x; acc[0][1] += a.x*b.y; acc[0][2] += a.x*b.z; acc[0][3] += a.x*b.w;
            acc[1][0] += a.y*b.x; acc[1][1] += a.y*b.y; acc[1][2] += a.y*b.z; acc[1][3] += a.y*b.w;
            acc[2][0] += a.z*b.x; acc[2][1] += a.z*b.y; acc[2][2] += a.z*b.z; acc[2][3] += a.z*b.w;
            acc[3][0] += a.w*b.x; acc[3][1] += a.w*b.y; acc[3][2] += a.w*b.z; acc[3][3] += a.w*b.w;
        }
    }
#pragma unroll
    for (int i = 0; i < 4; ++i)
#pragma unroll
        for (int j = 0; j < 4; ++j)
            part[(size_t)kb * 131072 + (size_t)(m0 + tm * 4 + i) * 128 + (n0 + tn * 4 + j)] = acc[i][j];
}

__global__ __launch_bounds__(128) void fc2_kernel(
    const float* __restrict__ part, const float* __restrict__ fb1,
    const float* __restrict__ fw2, const float* __restrict__ fb2, float* __restrict__ angO)
{
    __shared__ float h[128];
    const int b = blockIdx.x, t = threadIdx.x;
    float s = fb1[t];
#pragma unroll
    for (int kb = 0; kb < 8; ++kb) s += part[(size_t)kb * 131072 + b * 128 + t];
    h[t] = fmaxf(s, 0.f);
    __syncthreads();
    if (t < 10) {
        float d = fb2[t];
#pragma unroll 16
        for (int k = 0; k < 128; ++k) d += h[k] * fw2[t * 128 + k];
        angO[b * 10 + t] = 6.283185307179586f / (1.f + expf(-d));
    }
}

__global__ __launch_bounds__(512) void circuit_kernel(
    const float* __restrict__ ang_g,
    const float* __restrict__ q_rx, const float* __restrict__ q_rz3,
    const float* __restrict__ q_ps6, const float* __restrict__ q_rot7,
    const float* __restrict__ q_mrz8, const float* __restrict__ q_crx9,
    const float* __restrict__ q_cry10, const float* __restrict__ q_crz11,
    const float* __restrict__ q_u2, const float* __restrict__ q_u3,
    float* __restrict__ out)
{
    __shared__ float2 st[1024];
    __shared__ float red[8][10];
    __shared__ float evs[10];
    const int b = blockIdx.x, t = threadIdx.x;
    float a[10];
#pragma unroll
    for (int j = 0; j < 10; ++j) a[j] = ang_g[b * 10 + j];
    run_circ(st, red, evs, t, a, q_rx, q_rz3, q_ps6, q_rot7, q_mrz8,
             q_crx9, q_cry10, q_crz11, q_u2, q_u3, out + b * 10);
}

// ===================== FALLBACK: fully fused fp32, zero workspace =====================
template <int NT>
__device__ __forceinline__ void conv_stage(
    float* buf, int n, int t,
    const float* __restrict__ x, const float* __restrict__ w1, const float* __restrict__ b1,
    const float* __restrict__ w2, const float* __restrict__ b2)
{
    float* xs  = buf;
    float* w1s = buf + 784;
    float* h1s = buf + 1072;
    float* w2s = buf + 1748;
    const int ocq = t / 24, r = t - ocq * 24;
    const bool active = (t < 384);

    for (int i = t; i < 784; i += NT) xs[i] = x[n * 784 + i];
    for (int i = t; i < 288; i += NT) w1s[i] = w1[i];

    float acc[4][24];
#pragma unroll
    for (int j = 0; j < 4; ++j)
#pragma unroll
        for (int xo = 0; xo < 24; ++xo) acc[j][xo] = 0.f;

    for (int ic = 0; ic < 32; ++ic) {
        __syncthreads();
        float bb1 = b1[ic];
        for (int i = t; i < 676; i += NT) {
            int yy = i / 26, xx = i - yy * 26;
            const float* xp = xs + yy * 28 + xx;
            const float* wp = w1s + ic * 9;
            float s = bb1;
#pragma unroll
            for (int ky = 0; ky < 3; ++ky)
#pragma unroll
                for (int kx = 0; kx < 3; ++kx)
                    s += xp[ky * 28 + kx] * wp[ky * 3 + kx];
            h1s[i] = fmaxf(s, 0.f);
        }
        for (int i = t; i < 576; i += NT) {
            int oc = i / 9, k = i - oc * 9;
            w2s[i] = w2[oc * 288 + ic * 9 + k];
        }
        __syncthreads();
        if (active) {
            float wr[4][9];
#pragma unroll
            for (int j = 0; j < 4; ++j)
#pragma unroll
                for (int k = 0; k < 9; ++k)
                    wr[j][k] = w2s[(ocq * 4 + j) * 9 + k];
            float c0[3], c1[3];
#pragma unroll
            for (int q = 0; q < 3; ++q) { c0[q] = h1s[(r + q) * 26]; c1[q] = h1s[(r + q) * 26 + 1]; }
#pragma unroll
            for (int xo = 0; xo < 24; ++xo) {
                float c2[3];
#pragma unroll
                for (int q = 0; q < 3; ++q) c2[q] = h1s[(r + q) * 26 + xo + 2];
#pragma unroll
                for (int j = 0; j < 4; ++j) {
                    acc[j][xo] += wr[j][0]*c0[0] + wr[j][1]*c1[0] + wr[j][2]*c2[0]
                                + wr[j][3]*c0[1] + wr[j][4]*c1[1] + wr[j][5]*c2[1]
                                + wr[j][6]*c0[2] + wr[j][7]*c1[2] + wr[j][8]*c2[2];
                }
#pragma unroll
                for (int q = 0; q < 3; ++q) { c0[q] = c1[q]; c1[q] = c2[q]; }
            }
        }
    }
    __syncthreads();
    if (active && (r & 1)) {
#pragma unroll
        for (int j = 0; j < 4; ++j) {
            int oc = ocq * 4 + j;
            float bb = b2[oc];
#pragma unroll
            for (int px = 0; px < 12; ++px) {
                float v0 = fmaxf(acc[j][2*px]   + bb, 0.f);
                float v1 = fmaxf(acc[j][2*px+1] + bb, 0.f);
                buf[oc * 144 + (r >> 1) * 12 + px] = fmaxf(v0, v1);
            }
        }
    }
    __syncthreads();
    if (active && !(r & 1)) {
#pragma unroll
        for (int j = 0; j < 4; ++j) {
            int oc = ocq * 4 + j;
            float bb = b2[oc];
#pragma unroll
            for (int px = 0; px < 12; ++px) {
                float v0 = fmaxf(acc[j][2*px]   + bb, 0.f);
                float v1 = fmaxf(acc[j][2*px+1] + bb, 0.f);
                int idx = oc * 144 + (r >> 1) * 12 + px;
                buf[idx] = fmaxf(fmaxf(v0, v1), buf[idx]);
            }
        }
    }
    __syncthreads();
}

__global__ __launch_bounds__(512) void fused_kernel(
    const float* __restrict__ x, const float* __restrict__ w1, const float* __restrict__ b1,
    const float* __restrict__ w2, const float* __restrict__ b2,
    const float* __restrict__ fw1, const float* __restrict__ fb1,
    const float* __restrict__ fw2, const float* __restrict__ fb2,
    const float* __restrict__ q_rx, const float* __restrict__ q_rz3,
    const float* __restrict__ q_ps6, const float* __restrict__ q_rot7,
    const float* __restrict__ q_mrz8, const float* __restrict__ q_crx9,
    const float* __restrict__ q_cry10, const float* __restrict__ q_crz11,
    const float* __restrict__ q_u2, const float* __restrict__ q_u3,
    float* __restrict__ out)
{
    __shared__ float buf[9216];
    __shared__ float2 st[1024];
    __shared__ float hred[512];
    __shared__ float hvec[128];
    __shared__ float angs[10];
    __shared__ float red[8][10];
    __shared__ float evs[10];
    const int n = blockIdx.x, t = threadIdx.x;

    conv_stage<512>(buf, n, t, x, w1, b1, w2, b2);

    {
        const int j = t >> 2, q = t & 3;
        const float* wrow = fw1 + (size_t)j * 9216 + q * 2304;
        const float* arow = buf + q * 2304;
        float s = 0.f;
        for (int k = 0; k < 2304; k += 4) {
            float4 w = *(const float4*)(wrow + k);
            s += w.x * arow[k] + w.y * arow[k+1] + w.z * arow[k+2] + w.w * arow[k+3];
        }
        hred[t] = s;
    }
    __syncthreads();
    if (t < 128)
        hvec[t] = fmaxf(fb1[t] + hred[t*4] + hred[t*4+1] + hred[t*4+2] + hred[t*4+3], 0.f);
    __syncthreads();
    if (t < 10) {
        float d = fb2[t];
#pragma unroll 16
        for (int k = 0; k < 128; ++k) d += hvec[k] * fw2[t * 128 + k];
        angs[t] = 6.283185307179586f / (1.f + expf(-d));
    }
    __syncthreads();
    run_circ(st, red, evs, t, angs, q_rx, q_rz3, q_ps6, q_rot7, q_mrz8,
             q_crx9, q_cry10, q_crz11, q_u2, q_u3, out + n * 10);
}

// ===================== launch =====================
extern "C" void kernel_launch(void* const* d_in, const int* in_sizes, int n_in,
                              void* d_out, int out_size, void* d_ws, size_t ws_size,
                              hipStream_t stream)
{
    (void)in_sizes; (void)n_in;
    const float* x    = (const float*)d_in[0];
    const float* w1   = (const float*)d_in[1];
    const float* b1   = (const float*)d_in[2];
    const float* w2   = (const float*)d_in[3];
    const float* b2   = (const float*)d_in[4];
    const float* fw1  = (const float*)d_in[5];
    const float* fb1  = (const float*)d_in[6];
    const float* fw2  = (const float*)d_in[7];
    const float* fb2  = (const float*)d_in[8];
    const float* qrx  = (const float*)d_in[9];
    const float* qrz3 = (const float*)d_in[10];
    const float* qps6 = (const float*)d_in[11];
    const float* qrot7 = (const float*)d_in[12];
    const float* qmrz8 = (const float*)d_in[13];
    const float* qcrx9 = (const float*)d_in[14];
    const float* qcry10 = (const float*)d_in[15];
    const float* qcrz11 = (const float*)d_in[16];
    const float* qu2  = (const float*)d_in[17];
    const float* qu3  = (const float*)d_in[18];
    float* out = (float*)d_out;

    const size_t flat_sz = (size_t)1024 * 9216;          // fp32
    const size_t part_sz = (size_t)8 * 1024 * 128;       // fp32
    const size_t ang_sz  = (size_t)1024 * 10;            // fp32
    const size_t w2t_off = (flat_sz + part_sz + ang_sz) * 4;  // bytes (16-aligned)
    const size_t need = w2t_off + 18432 * 2;

    (void)hipGetLastError();  // clear stale errors

    if (ws_size >= need) {
        float* flat = (float*)d_ws;
        float* part = flat + flat_sz;
        float* angb = part + part_sz;
        unsigned short* w2t = (unsigned short*)((char*)d_ws + w2t_off);
        prep_w2<<<72, 256, 0, stream>>>(w2, w2t);
        convnet_mfma<<<1024, 256, 0, stream>>>(x, w1, b1, w2t, b2, flat);
        fc1_kernel<<<dim3(16, 2, 8), 256, 0, stream>>>(flat, fw1, part);
        fc2_kernel<<<1024, 128, 0, stream>>>(part, fb1, fw2, fb2, angb);
        circuit_kernel<<<1024, 512, 0, stream>>>(angb, qrx, qrz3, qps6, qrot7, qmrz8,
                                                 qcrx9, qcry10, qcrz11, qu2, qu3, out);
    } else {
        fused_kernel<<<1024, 512, 0, stream>>>(x, w1, b1, w2, b2, fw1, fb1, fw2, fb2,
                                               qrx, qrz3, qps6, qrot7, qmrz8,
                                               qcrx9, qcry10, qcrz11, qu2, qu3, out);
    }
    if (hipGetLastError() != hipSuccess) {
        (void)hipMemsetAsync(d_out, 0x7F, (size_t)out_size * 2, stream);
    }
}

// Round 5
// 204.752 us; speedup vs baseline: 3.2036x; 1.1572x over previous
//
#include <hip/hip_runtime.h>
#include <hip/hip_bf16.h>

#define PI_F 3.14159265358979323846f

// Loader insurance: keep a kernel with the stub's exact name (not launched).
__global__ void Static_82300163326800_kernel() {}

typedef _Float16 f16x8 __attribute__((ext_vector_type(8)));
typedef _Float16 f16x4 __attribute__((ext_vector_type(4)));
typedef float f32x4 __attribute__((ext_vector_type(4)));

// ===================== quantum circuit (shared device code) =====================
struct M2 { float2 m00, m01, m10, m11; };

__device__ __forceinline__ int ins1(int x, int p) {
    return ((x >> p) << (p + 1)) | (x & ((1 << p) - 1));
}
__device__ __forceinline__ M2 mrx(float th) {
    float s, c; __sincosf(0.5f * th, &s, &c);
    return { make_float2(c,0.f), make_float2(0.f,-s), make_float2(0.f,-s), make_float2(c,0.f) };
}
__device__ __forceinline__ M2 mry(float th) {
    float s, c; __sincosf(0.5f * th, &s, &c);
    return { make_float2(c,0.f), make_float2(-s,0.f), make_float2(s,0.f), make_float2(c,0.f) };
}
__device__ __forceinline__ M2 mrot(float phi, float th, float om) {
    float s, c;  __sincosf(0.5f * th, &s, &c);
    float sa, ca; __sincosf(0.5f * (phi + om), &sa, &ca);
    float sd, cd; __sincosf(0.5f * (phi - om), &sd, &cd);
    return { make_float2(ca*c, -sa*c), make_float2(-cd*s, -sd*s),
             make_float2(cd*s, -sd*s), make_float2(ca*c,  sa*c) };
}
__device__ __forceinline__ M2 mu2(float phi, float lam) {
    const float r = 0.7071067811865476f;
    float sl, cl;   __sincosf(lam, &sl, &cl);
    float sp, cp;   __sincosf(phi, &sp, &cp);
    float spl, cpl; __sincosf(phi + lam, &spl, &cpl);
    return { make_float2(r,0.f), make_float2(-r*cl,-r*sl),
             make_float2(r*cp, r*sp), make_float2(r*cpl, r*spl) };
}
__device__ __forceinline__ M2 mu3(float th, float phi, float lam) {
    float s, c;     __sincosf(0.5f * th, &s, &c);
    float sl, cl;   __sincosf(lam, &sl, &cl);
    float sp, cp;   __sincosf(phi, &sp, &cp);
    float spl, cpl; __sincosf(phi + lam, &spl, &cpl);
    return { make_float2(c,0.f), make_float2(-cl*s,-sl*s),
             make_float2(cp*s, sp*s), make_float2(cpl*c, spl*c) };
}
__device__ __forceinline__ void apply1(float2* st, int t, int w, M2 m) {
    int p = 9 - w;
    int i0 = ins1(t, p), i1 = i0 | (1 << p);
    float2 a = st[i0], d = st[i1];
    st[i0] = make_float2(m.m00.x*a.x - m.m00.y*a.y + m.m01.x*d.x - m.m01.y*d.y,
                         m.m00.x*a.y + m.m00.y*a.x + m.m01.x*d.y + m.m01.y*d.x);
    st[i1] = make_float2(m.m10.x*a.x - m.m10.y*a.y + m.m11.x*d.x - m.m11.y*d.y,
                         m.m10.x*a.y + m.m10.y*a.x + m.m11.x*d.y + m.m11.y*d.x);
}
__device__ __forceinline__ void diag1(float2* st, int t, int w, float2 d0, float2 d1) {
    int p = 9 - w;
    int i0 = ins1(t, p), i1 = i0 | (1 << p);
    float2 a = st[i0], c = st[i1];
    st[i0] = make_float2(d0.x*a.x - d0.y*a.y, d0.x*a.y + d0.y*a.x);
    st[i1] = make_float2(d1.x*c.x - d1.y*c.y, d1.x*c.y + d1.y*c.x);
}
__device__ __forceinline__ void capply1(float2* st, int t, int c, int w, M2 m) {
    if (t < 256) {
        int pc = 9 - c, pw = 9 - w;
        int pl = pc < pw ? pc : pw, ph = pc + pw - pl;
        int base = ins1(ins1(t, pl), ph) | (1 << pc);
        int i0 = base, i1 = base | (1 << pw);
        float2 a = st[i0], d = st[i1];
        st[i0] = make_float2(m.m00.x*a.x - m.m00.y*a.y + m.m01.x*d.x - m.m01.y*d.y,
                             m.m00.x*a.y + m.m00.y*a.x + m.m01.x*d.y + m.m01.y*d.x);
        st[i1] = make_float2(m.m10.x*a.x - m.m10.y*a.y + m.m11.x*d.x - m.m11.y*d.y,
                             m.m10.x*a.y + m.m10.y*a.x + m.m11.x*d.y + m.m11.y*d.x);
    }
}
__device__ __forceinline__ void cdiag1(float2* st, int t, int c, int w, float2 d0, float2 d1) {
    if (t < 256) {
        int pc = 9 - c, pw = 9 - w;
        int pl = pc < pw ? pc : pw, ph = pc + pw - pl;
        int base = ins1(ins1(t, pl), ph) | (1 << pc);
        int i0 = base, i1 = base | (1 << pw);
        float2 a = st[i0], e = st[i1];
        st[i0] = make_float2(d0.x*a.x - d0.y*a.y, d0.x*a.y + d0.y*a.x);
        st[i1] = make_float2(d1.x*e.x - d1.y*e.y, d1.x*e.y + d1.y*e.x);
    }
}
__device__ __forceinline__ void cnotg(float2* st, int t, int c, int w) {
    if (t < 256) {
        int pc = 9 - c, pw = 9 - w;
        int pl = pc < pw ? pc : pw, ph = pc + pw - pl;
        int base = ins1(ins1(t, pl), ph) | (1 << pc);
        int i1 = base | (1 << pw);
        float2 a = st[base]; st[base] = st[i1]; st[i1] = a;
    }
}
__device__ __forceinline__ void czg(float2* st, int t, int c, int w) {
    if (t < 256) {
        int pc = 9 - c, pw = 9 - w;
        int pl = pc < pw ? pc : pw, ph = pc + pw - pl;
        int i = ins1(ins1(t, pl), ph) | (1 << pc) | (1 << pw);
        st[i] = make_float2(-st[i].x, -st[i].y);
    }
}
__device__ __forceinline__ void swapg(float2* st, int t, int a, int b_) {
    if (t < 256) {
        int pa = 9 - a, pb = 9 - b_;
        int pl = pa < pb ? pa : pb, ph = pa + pb - pl;
        int base = ins1(ins1(t, pl), ph);
        int iA = base | (1 << pa), iB = base | (1 << pb);
        float2 u = st[iA]; st[iA] = st[iB]; st[iB] = u;
    }
}
__device__ __forceinline__ void cswap456(float2* st, int t) {
    if (t < 128) {
        int base = ins1(ins1(ins1(t, 3), 4), 5) | (1 << 5);
        int iA = base | (1 << 4), iB = base | (1 << 3);
        float2 u = st[iA]; st[iA] = st[iB]; st[iB] = u;
    }
}
__device__ __forceinline__ void toff850(float2* st, int t) {
    if (t < 128) {
        int base = ins1(ins1(ins1(t, 1), 4), 9) | (1 << 1) | (1 << 4);
        int i1 = base | (1 << 9);
        float2 u = st[base]; st[base] = st[i1]; st[i1] = u;
    }
}
__device__ __forceinline__ void mrzg(float2* st, int t, int mask, float th) {
    float sh, ch; __sincosf(0.5f * th, &sh, &ch);
#pragma unroll
    for (int q = 0; q < 2; ++q) {
        int i = t + q * 512;
        float sg = (__popc(i & mask) & 1) ? sh : -sh;
        float2 a = st[i];
        st[i] = make_float2(ch*a.x - sg*a.y, ch*a.y + sg*a.x);
    }
}

__device__ __forceinline__ void run_circ(
    float2* st, float (*red)[10], float* evs, int t, const float* ang,
    const float* q_rx, const float* q_rz3, const float* q_ps6, const float* q_rot7,
    const float* q_mrz8, const float* q_crx9, const float* q_cry10, const float* q_crz11,
    const float* q_u2, const float* q_u3, float* outf)
{
    st[t] = make_float2(t == 0 ? 1.f : 0.f, 0.f);
    st[t + 512] = make_float2(0.f, 0.f);

#pragma unroll
    for (int k = 0; k < 10; ++k) { M2 m = mrx(q_rx[k]); __syncthreads(); apply1(st, t, k, m); }
    {
        M2 mx0 = mrx(ang[0]);
#pragma unroll
        for (int k = 0; k < 10; ++k) {
            M2 m = mry(ang[k]); __syncthreads(); apply1(st, t, k, m);
            __syncthreads(); apply1(st, t, 0, mx0);
        }
    }
#pragma unroll
    for (int k = 0; k < 9; ++k) { __syncthreads(); cnotg(st, t, k, k + 1); }
    __syncthreads(); cnotg(st, t, 9, 0);

    { M2 m = mrx(ang[1]);      __syncthreads(); apply1(st, t, 1, m); }
    { M2 m = mrx(-PI_F / 4.f); __syncthreads(); apply1(st, t, 5, m); }
    { M2 m = mry(ang[2]);      __syncthreads(); apply1(st, t, 2, m); }
    { float s, c; __sincosf(0.5f * ang[3], &s, &c);
      __syncthreads(); diag1(st, t, 3, make_float2(c,-s), make_float2(c,s)); }
    __syncthreads(); diag1(st, t, 4, make_float2(1.f,0.f), make_float2(0.f,1.f));  // S
    __syncthreads(); diag1(st, t, 5, make_float2(1.f,0.f),
                           make_float2(0.7071067811865476f, 0.7071067811865476f)); // T
    { float s, c; __sincosf(0.5f * q_rz3[0], &s, &c);
      __syncthreads(); diag1(st, t, 6, make_float2(c,-s), make_float2(c,s)); }
    { M2 m = { make_float2(0.5f,0.5f), make_float2(0.5f,-0.5f),
               make_float2(0.5f,-0.5f), make_float2(0.5f,0.5f) };
      __syncthreads(); apply1(st, t, 7, m); }                                      // SX
    __syncthreads(); czg(st, t, 0, 5);
    __syncthreads(); cnotg(st, t, 0, 5);
    { M2 y = { make_float2(0.f,0.f), make_float2(0.f,-1.f),
               make_float2(0.f,1.f), make_float2(0.f,0.f) };
      __syncthreads(); capply1(st, t, 0, 5, y);
      __syncthreads(); capply1(st, t, 3, 8, y); }
    __syncthreads(); swapg(st, t, 2, 3);
    __syncthreads(); cswap456(st, t);
    __syncthreads(); toff850(st, t);
    { float s, c; __sincosf(q_ps6[0], &s, &c);
      __syncthreads(); diag1(st, t, 8, make_float2(1.f,0.f), make_float2(c,s)); }
    { float s, c; __sincosf(ang[7], &s, &c);
      __syncthreads(); diag1(st, t, 7, make_float2(1.f,0.f), make_float2(c,s)); }
    { M2 m = mrot(q_rot7[0], q_rot7[1], q_rot7[2]); __syncthreads(); apply1(st, t, 4, m); }
    { M2 m = mrot(ang[6], ang[7], ang[8]);          __syncthreads(); apply1(st, t, 5, m); }
    __syncthreads(); mrzg(st, t, 0xF8, q_mrz8[0]);  // wires (2,3,4,5,6)
    __syncthreads(); mrzg(st, t, 0x6E, ang[5]);     // wires (3,4,6,7,8)
    { M2 m = mrx(ang[6]);      __syncthreads(); capply1(st, t, 0, 1, m); }
    { M2 m = mrx(q_crx9[0]);   __syncthreads(); capply1(st, t, 4, 5, m); }
    { M2 m = mry(ang[6]);      __syncthreads(); capply1(st, t, 0, 1, m); }
    { M2 m = mry(q_cry10[0]);  __syncthreads(); capply1(st, t, 4, 5, m); }
    { float s, c; __sincosf(0.5f * ang[6], &s, &c);
      __syncthreads(); cdiag1(st, t, 0, 1, make_float2(c,-s), make_float2(c,s)); }
    { float s, c; __sincosf(0.5f * q_crz11[0], &s, &c);
      __syncthreads(); cdiag1(st, t, 4, 5, make_float2(c,-s), make_float2(c,s)); }
    { M2 m = mrot(-PI_F/4.f, PI_F/4.f, PI_F/2.f); __syncthreads(); capply1(st, t, 5, 6, m); }
    { M2 m = mrot(ang[5], ang[6], ang[7]);        __syncthreads(); capply1(st, t, 7, 8, m); }
    { float s, c; __sincosf(PI_F/7.f, &s, &c);
      __syncthreads(); diag1(st, t, 1, make_float2(1.f,0.f), make_float2(c,s)); } // U1
    { float s, c; __sincosf(ang[9], &s, &c);
      __syncthreads(); diag1(st, t, 2, make_float2(1.f,0.f), make_float2(c,s)); }
    { M2 m = mu2(q_u2[0], q_u2[1]); __syncthreads(); apply1(st, t, 8, m); }
    { M2 m = mu2(ang[0], ang[1]);   __syncthreads(); apply1(st, t, 4, m); }
    { M2 m = mu3(q_u3[0], q_u3[1], q_u3[2]); __syncthreads(); apply1(st, t, 5, m); }
    { M2 m = mu3(ang[4], ang[5], ang[6]);    __syncthreads(); apply1(st, t, 5, m); }
    __syncthreads(); cnotg(st, t, 1, 2);
    __syncthreads();

    float loc[10];
#pragma unroll
    for (int w = 0; w < 10; ++w) {
        int p = 9 - w;
        int i0 = ins1(t, p), i1 = i0 | (1 << p);
        float2 a = st[i0], c = st[i1];
        loc[w] = 2.f * (a.x * c.y - a.y * c.x);
    }
    int lane = t & 63, wv = t >> 6;
#pragma unroll
    for (int w = 0; w < 10; ++w) {
        float v = loc[w];
        v += __shfl_down(v, 32); v += __shfl_down(v, 16); v += __shfl_down(v, 8);
        v += __shfl_down(v, 4);  v += __shfl_down(v, 2);  v += __shfl_down(v, 1);
        if (lane == 0) red[wv][w] = v;
    }
    __syncthreads();
    if (t < 10) {
        float e = 0.f;
#pragma unroll
        for (int i = 0; i < 8; ++i) e += red[i][t];
        evs[t] = e;
    }
    __syncthreads();
    if (t < 10) {
        float mx = evs[0];
#pragma unroll
        for (int i = 1; i < 10; ++i) mx = fmaxf(mx, evs[i]);
        float ss = 0.f;
#pragma unroll
        for (int i = 0; i < 10; ++i) ss += expf(evs[i] - mx);
        outf[t] = evs[t] - mx - logf(ss);
    }
}

// ===================== prep: w2 [64][32][3][3] fp32 -> w2t [64][9*32] f16 ==========
__global__ __launch_bounds__(256) void prep_w2(
    const float* __restrict__ w2, _Float16* __restrict__ w2t)
{
    int idx = blockIdx.x * 256 + threadIdx.x;
    if (idx < 18432) {
        int oc = idx / 288, r = idx - oc * 288;
        int s = r >> 5, ic = r & 31;
        w2t[idx] = (_Float16)w2[oc * 288 + ic * 9 + s];
    }
}

// ===================== prep: fw1 [128][9216] fp32 -> f16 =====================
__global__ __launch_bounds__(256) void prep_fw1(
    const float* __restrict__ fw1, _Float16* __restrict__ out)
{
    int i = blockIdx.x * 256 + threadIdx.x;   // 294912 float4 groups
    if (i < 294912) {
        float4 v = ((const float4*)fw1)[i];
        f16x4 o = { (_Float16)v.x, (_Float16)v.y, (_Float16)v.z, (_Float16)v.w };
        *(f16x4*)(out + i * 4) = o;
    }
}

// ===================== MFMA convnet: conv1(fp32)->f16 LDS, conv2 via MFMA ==========
// grid 1024 (one image per block), block 256 (4 waves). Output flat is f16.
__global__ __launch_bounds__(256, 2) void convnet_mfma(
    const float* __restrict__ x, const float* __restrict__ w1, const float* __restrict__ b1,
    const _Float16* __restrict__ w2t, const float* __restrict__ b2,
    _Float16* __restrict__ flat)
{
    __shared__ float xs[784];
    __shared__ float w1s[288];
    __shared__ __align__(16) _Float16 h1t[676 * 40];  // [pix][ic], stride 40
    const int n = blockIdx.x, t = threadIdx.x;
    const int lane = t & 63, wv = t >> 6;
    const int m = lane & 15, quad = lane >> 4;

    for (int i = t; i < 784; i += 256) xs[i] = x[n * 784 + i];
    for (int i = t; i < 288; i += 256) w1s[i] = w1[i];

    bf16x8_dummy: ;  // (label removed below -- placeholder never used)
    f16x8 bq[9][4];
#pragma unroll
    for (int s = 0; s < 9; ++s)
#pragma unroll
        for (int nt = 0; nt < 4; ++nt)
            bq[s][nt] = *(const f16x8*)(w2t + (nt * 16 + m) * 288 + s * 32 + quad * 8);

    __syncthreads();

    {
        const int ic = t & 31;
        float wr[9];
#pragma unroll
        for (int k = 0; k < 9; ++k) wr[k] = w1s[ic * 9 + k];
        const float bb = b1[ic];
        for (int pix = (t >> 5); pix < 676; pix += 8) {
            int yy = pix / 26, xx = pix - yy * 26;
            const float* xp = xs + yy * 28 + xx;
            float s = bb;
            s += xp[0]*wr[0]  + xp[1]*wr[1]  + xp[2]*wr[2]
               + xp[28]*wr[3] + xp[29]*wr[4] + xp[30]*wr[5]
               + xp[56]*wr[6] + xp[57]*wr[7] + xp[58]*wr[8];
            h1t[pix * 40 + ic] = (_Float16)fmaxf(s, 0.f);
        }
    }
    __syncthreads();

    float bb2[4];
#pragma unroll
    for (int nt = 0; nt < 4; ++nt) bb2[nt] = b2[nt * 16 + m];

    _Float16* outp = flat + (size_t)n * 9216;

    for (int q = 0; q < 9; ++q) {
        const int mt = wv + q * 4;
        const int a = mt / 3, b3 = mt - a * 3;
        const int y0 = 2 * a + (m & 1), x0 = 8 * b3 + (m >> 1);
        f32x4 acc[4] = {};
#pragma unroll
        for (int s = 0; s < 9; ++s) {
            const int ky = s / 3, kx = s - ky * 3;
            f16x8 af = *(const f16x8*)&h1t[((y0 + ky) * 26 + x0 + kx) * 40 + quad * 8];
#pragma unroll
            for (int nt = 0; nt < 4; ++nt)
                acc[nt] = __builtin_amdgcn_mfma_f32_16x16x32_f16(af, bq[s][nt], acc[nt], 0, 0, 0);
        }
        const int pooled_idx = a * 12 + 4 * b3 + quad;
#pragma unroll
        for (int nt = 0; nt < 4; ++nt) {
            float v = fmaxf(fmaxf(acc[nt][0], acc[nt][1]), fmaxf(acc[nt][2], acc[nt][3]));
            outp[(nt * 16 + m) * 144 + pooled_idx] = (_Float16)fmaxf(v + bb2[nt], 0.f);
        }
    }
}

// ===================== fc1 MFMA: [1024,9216]f16 @ [128,9216]^T f16, K split 16 ======
// grid (16,2,16), block 256 (4 waves). Wave = 16-row m-tile x 64 cols (4 n-tiles).
__global__ __launch_bounds__(256) void fc1_mfma(
    const _Float16* __restrict__ A, const _Float16* __restrict__ B, float* __restrict__ part)
{
    const int m0 = blockIdx.x * 64, n0 = blockIdx.y * 64, kb = blockIdx.z;
    const int t = threadIdx.x, lane = t & 63, wv = t >> 6;
    const int r = lane & 15, quad = lane >> 4;
    const _Float16* ap = A + (size_t)(m0 + wv * 16 + r) * 9216 + kb * 576 + quad * 8;
    const _Float16* bp = B + (size_t)(n0 + r) * 9216 + kb * 576 + quad * 8;
    f32x4 acc[4] = {};
    for (int ks = 0; ks < 576; ks += 32) {
        f16x8 af = *(const f16x8*)(ap + ks);
#pragma unroll
        for (int nt = 0; nt < 4; ++nt) {
            f16x8 bfr = *(const f16x8*)(bp + (size_t)nt * 16 * 9216 + ks);
            acc[nt] = __builtin_amdgcn_mfma_f32_16x16x32_f16(af, bfr, acc[nt], 0, 0, 0);
        }
    }
    // D: row = quad*4+reg (within m-tile), col = r (within n-tile)
    float* pp = part + (size_t)kb * 131072 + (size_t)(m0 + wv * 16 + quad * 4) * 128 + n0 + r;
#pragma unroll
    for (int nt = 0; nt < 4; ++nt)
#pragma unroll
        for (int reg = 0; reg < 4; ++reg)
            pp[reg * 128 + nt * 16] = acc[nt][reg];
}

// ===================== fc2 + sigmoid*2pi (sums 16 split-K slabs) =====================
__global__ __launch_bounds__(128) void fc2_kernel(
    const float* __restrict__ part, const float* __restrict__ fb1,
    const float* __restrict__ fw2, const float* __restrict__ fb2, float* __restrict__ angO)
{
    __shared__ float h[128];
    const int b = blockIdx.x, t = threadIdx.x;
    float s = fb1[t];
#pragma unroll
    for (int kb = 0; kb < 16; ++kb) s += part[(size_t)kb * 131072 + b * 128 + t];
    h[t] = fmaxf(s, 0.f);
    __syncthreads();
    if (t < 10) {
        float d = fb2[t];
#pragma unroll 16
        for (int k = 0; k < 128; ++k) d += h[k] * fw2[t * 128 + k];
        angO[b * 10 + t] = 6.283185307179586f / (1.f + expf(-d));
    }
}

__global__ __launch_bounds__(512) void circuit_kernel(
    const float* __restrict__ ang_g,
    const float* __restrict__ q_rx, const float* __restrict__ q_rz3,
    const float* __restrict__ q_ps6, const float* __restrict__ q_rot7,
    const float* __restrict__ q_mrz8, const float* __restrict__ q_crx9,
    const float* __restrict__ q_cry10, const float* __restrict__ q_crz11,
    const float* __restrict__ q_u2, const float* __restrict__ q_u3,
    float* __restrict__ out)
{
    __shared__ float2 st[1024];
    __shared__ float red[8][10];
    __shared__ float evs[10];
    const int b = blockIdx.x, t = threadIdx.x;
    float a[10];
#pragma unroll
    for (int j = 0; j < 10; ++j) a[j] = ang_g[b * 10 + j];
    run_circ(st, red, evs, t, a, q_rx, q_rz3, q_ps6, q_rot7, q_mrz8,
             q_crx9, q_cry10, q_crz11, q_u2, q_u3, out + b * 10);
}

// ===================== FALLBACK: fully fused fp32, zero workspace =====================
template <int NT>
__device__ __forceinline__ void conv_stage(
    float* buf, int n, int t,
    const float* __restrict__ x, const float* __restrict__ w1, const float* __restrict__ b1,
    const float* __restrict__ w2, const float* __restrict__ b2)
{
    float* xs  = buf;
    float* w1s = buf + 784;
    float* h1s = buf + 1072;
    float* w2s = buf + 1748;
    const int ocq = t / 24, r = t - ocq * 24;
    const bool active = (t < 384);

    for (int i = t; i < 784; i += NT) xs[i] = x[n * 784 + i];
    for (int i = t; i < 288; i += NT) w1s[i] = w1[i];

    float acc[4][24];
#pragma unroll
    for (int j = 0; j < 4; ++j)
#pragma unroll
        for (int xo = 0; xo < 24; ++xo) acc[j][xo] = 0.f;

    for (int ic = 0; ic < 32; ++ic) {
        __syncthreads();
        float bb1 = b1[ic];
        for (int i = t; i < 676; i += NT) {
            int yy = i / 26, xx = i - yy * 26;
            const float* xp = xs + yy * 28 + xx;
            const float* wp = w1s + ic * 9;
            float s = bb1;
#pragma unroll
            for (int ky = 0; ky < 3; ++ky)
#pragma unroll
                for (int kx = 0; kx < 3; ++kx)
                    s += xp[ky * 28 + kx] * wp[ky * 3 + kx];
            h1s[i] = fmaxf(s, 0.f);
        }
        for (int i = t; i < 576; i += NT) {
            int oc = i / 9, k = i - oc * 9;
            w2s[i] = w2[oc * 288 + ic * 9 + k];
        }
        __syncthreads();
        if (active) {
            float wr[4][9];
#pragma unroll
            for (int j = 0; j < 4; ++j)
#pragma unroll
                for (int k = 0; k < 9; ++k)
                    wr[j][k] = w2s[(ocq * 4 + j) * 9 + k];
            float c0[3], c1[3];
#pragma unroll
            for (int q = 0; q < 3; ++q) { c0[q] = h1s[(r + q) * 26]; c1[q] = h1s[(r + q) * 26 + 1]; }
#pragma unroll
            for (int xo = 0; xo < 24; ++xo) {
                float c2[3];
#pragma unroll
                for (int q = 0; q < 3; ++q) c2[q] = h1s[(r + q) * 26 + xo + 2];
#pragma unroll
                for (int j = 0; j < 4; ++j) {
                    acc[j][xo] += wr[j][0]*c0[0] + wr[j][1]*c1[0] + wr[j][2]*c2[0]
                                + wr[j][3]*c0[1] + wr[j][4]*c1[1] + wr[j][5]*c2[1]
                                + wr[j][6]*c0[2] + wr[j][7]*c1[2] + wr[j][8]*c2[2];
                }
#pragma unroll
                for (int q = 0; q < 3; ++q) { c0[q] = c1[q]; c1[q] = c2[q]; }
            }
        }
    }
    __syncthreads();
    if (active && (r & 1)) {
#pragma unroll
        for (int j = 0; j < 4; ++j) {
            int oc = ocq * 4 + j;
            float bb = b2[oc];
#pragma unroll
            for (int px = 0; px < 12; ++px) {
                float v0 = fmaxf(acc[j][2*px]   + bb, 0.f);
                float v1 = fmaxf(acc[j][2*px+1] + bb, 0.f);
                buf[oc * 144 + (r >> 1) * 12 + px] = fmaxf(v0, v1);
            }
        }
    }
    __syncthreads();
    if (active && !(r & 1)) {
#pragma unroll
        for (int j = 0; j < 4; ++j) {
            int oc = ocq * 4 + j;
            float bb = b2[oc];
#pragma unroll
            for (int px = 0; px < 12; ++px) {
                float v0 = fmaxf(acc[j][2*px]   + bb, 0.f);
                float v1 = fmaxf(acc[j][2*px+1] + bb, 0.f);
                int idx = oc * 144 + (r >> 1) * 12 + px;
                buf[idx] = fmaxf(fmaxf(v0, v1), buf[idx]);
            }
        }
    }
    __syncthreads();
}

__global__ __launch_bounds__(512) void fused_kernel(
    const float* __restrict__ x, const float* __restrict__ w1, const float* __restrict__ b1,
    const float* __restrict__ w2, const float* __restrict__ b2,
    const float* __restrict__ fw1, const float* __restrict__ fb1,
    const float* __restrict__ fw2, const float* __restrict__ fb2,
    const float* __restrict__ q_rx, const float* __restrict__ q_rz3,
    const float* __restrict__ q_ps6, const float* __restrict__ q_rot7,
    const float* __restrict__ q_mrz8, const float* __restrict__ q_crx9,
    const float* __restrict__ q_cry10, const float* __restrict__ q_crz11,
    const float* __restrict__ q_u2, const float* __restrict__ q_u3,
    float* __restrict__ out)
{
    __shared__ float buf[9216];
    __shared__ float2 st[1024];
    __shared__ float hred[512];
    __shared__ float hvec[128];
    __shared__ float angs[10];
    __shared__ float red[8][10];
    __shared__ float evs[10];
    const int n = blockIdx.x, t = threadIdx.x;

    conv_stage<512>(buf, n, t, x, w1, b1, w2, b2);

    {
        const int j = t >> 2, q = t & 3;
        const float* wrow = fw1 + (size_t)j * 9216 + q * 2304;
        const float* arow = buf + q * 2304;
        float s = 0.f;
        for (int k = 0; k < 2304; k += 4) {
            float4 w = *(const float4*)(wrow + k);
            s += w.x * arow[k] + w.y * arow[k+1] + w.z * arow[k+2] + w.w * arow[k+3];
        }
        hred[t] = s;
    }
    __syncthreads();
    if (t < 128)
        hvec[t] = fmaxf(fb1[t] + hred[t*4] + hred[t*4+1] + hred[t*4+2] + hred[t*4+3], 0.f);
    __syncthreads();
    if (t < 10) {
        float d = fb2[t];
#pragma unroll 16
        for (int k = 0; k < 128; ++k) d += hvec[k] * fw2[t * 128 + k];
        angs[t] = 6.283185307179586f / (1.f + expf(-d));
    }
    __syncthreads();
    run_circ(st, red, evs, t, angs, q_rx, q_rz3, q_ps6, q_rot7, q_mrz8,
             q_crx9, q_cry10, q_crz11, q_u2, q_u3, out + n * 10);
}

// ===================== launch =====================
extern "C" void kernel_launch(void* const* d_in, const int* in_sizes, int n_in,
                              void* d_out, int out_size, void* d_ws, size_t ws_size,
                              hipStream_t stream)
{
    (void)in_sizes; (void)n_in;
    const float* x    = (const float*)d_in[0];
    const float* w1   = (const float*)d_in[1];
    const float* b1   = (const float*)d_in[2];
    const float* w2   = (const float*)d_in[3];
    const float* b2   = (const float*)d_in[4];
    const float* fw1  = (const float*)d_in[5];
    const float* fb1  = (const float*)d_in[6];
    const float* fw2  = (const float*)d_in[7];
    const float* fb2  = (const float*)d_in[8];
    const float* qrx  = (const float*)d_in[9];
    const float* qrz3 = (const float*)d_in[10];
    const float* qps6 = (const float*)d_in[11];
    const float* qrot7 = (const float*)d_in[12];
    const float* qmrz8 = (const float*)d_in[13];
    const float* qcrx9 = (const float*)d_in[14];
    const float* qcry10 = (const float*)d_in[15];
    const float* qcrz11 = (const float*)d_in[16];
    const float* qu2  = (const float*)d_in[17];
    const float* qu3  = (const float*)d_in[18];
    float* out = (float*)d_out;

    // workspace layout (all offsets 16B-aligned)
    const size_t flat_bytes = (size_t)1024 * 9216 * 2;        // f16 activations
    const size_t part_bytes = (size_t)16 * 1024 * 128 * 4;    // fp32 split-K partials
    const size_t ang_bytes  = (size_t)1024 * 10 * 4;
    const size_t w2t_bytes  = (size_t)18432 * 2;
    const size_t fw1h_bytes = (size_t)128 * 9216 * 2;
    const size_t o_flat = 0;
    const size_t o_part = o_flat + flat_bytes;
    const size_t o_ang  = o_part + part_bytes;
    const size_t o_w2t  = o_ang + ang_bytes;
    const size_t o_fw1h = o_w2t + w2t_bytes;
    const size_t need   = o_fw1h + fw1h_bytes;

    (void)hipGetLastError();

    if (ws_size >= need) {
        _Float16* flat = (_Float16*)((char*)d_ws + o_flat);
        float*    part = (float*)((char*)d_ws + o_part);
        float*    angb = (float*)((char*)d_ws + o_ang);
        _Float16* w2t  = (_Float16*)((char*)d_ws + o_w2t);
        _Float16* fw1h = (_Float16*)((char*)d_ws + o_fw1h);
        prep_w2<<<72, 256, 0, stream>>>(w2, w2t);
        prep_fw1<<<1152, 256, 0, stream>>>(fw1, fw1h);
        convnet_mfma<<<1024, 256, 0, stream>>>(x, w1, b1, w2t, b2, flat);
        fc1_mfma<<<dim3(16, 2, 16), 256, 0, stream>>>(flat, fw1h, part);
        fc2_kernel<<<1024, 128, 0, stream>>>(part, fb1, fw2, fb2, angb);
        circuit_kernel<<<1024, 512, 0, stream>>>(angb, qrx, qrz3, qps6, qrot7, qmrz8,
                                                 qcrx9, qcry10, qcrz11, qu2, qu3, out);
    } else {
        fused_kernel<<<1024, 512, 0, stream>>>(x, w1, b1, w2, b2, fw1, fb1, fw2, fb2,
                                               qrx, qrz3, qps6, qrot7, qmrz8,
                                               qcrx9, qcry10, qcrz11, qu2, qu3, out);
    }
    if (hipGetLastError() != hipSuccess) {
        (void)hipMemsetAsync(d_out, 0x7F, (size_t)out_size * 2, stream);
    }
}